// Round 8
// baseline (4821.834 us; speedup 1.0000x reference)
//
#include <hip/hip_runtime.h>

#define B_  128
#define S_  1024
#define H_  256
#define NM_ 16
#define NEG_INF_TGT (-0x7FFFFFFF)

typedef short bf16x8 __attribute__((ext_vector_type(8)));
typedef float f32x4  __attribute__((ext_vector_type(4)));

__device__ __forceinline__ short f2bf(float f) {
    unsigned u = __builtin_bit_cast(unsigned, f);
    unsigned r = (u + 0x7FFFu + ((u >> 16) & 1u)) >> 16;   // RNE
    return (short)r;
}
__device__ __forceinline__ bf16x8 zero8() {
    bf16x8 v;
    #pragma unroll
    for (int j = 0; j < 8; ++j) v[j] = 0;
    return v;
}
__device__ __forceinline__ float sigf(float x)  { return 1.0f / (1.0f + __expf(-x)); }
__device__ __forceinline__ float tanh_(float x) { return 1.0f - 2.0f / (1.0f + __expf(2.0f * x)); }
__device__ __forceinline__ void vm_drain() {
    asm volatile("s_waitcnt vmcnt(0)" ::: "memory");
}

// ---- sc0+sc1 (L2-bypass, coherence at L3) primitives — all R2/R5-proven shapes ----
__device__ __forceinline__ int cload_int(const int* p) {
    int r;
    asm volatile("global_load_dword %0, %1, off sc0 sc1\n\ts_waitcnt vmcnt(0)"
                 : "=v"(r) : "v"(p) : "memory");
    return r;
}
__device__ __forceinline__ void cstore_int(int* p, int v) {
    asm volatile("global_store_dword %0, %1, off sc0 sc1" :: "v"(p), "v"(v) : "memory");
}
__device__ __forceinline__ void cstore_short(short* p, int v) {
    asm volatile("global_store_short %0, %1, off sc0 sc1" :: "v"(p), "v"(v) : "memory");
}
// 8 x 16B coherent loads + internal waitcnt (outputs data-ready by construction).
__device__ __forceinline__ void cload8x16(const short* p, bf16x8* d) {
    int4 a0, a1, a2, a3, a4, a5, a6, a7;
    asm volatile(
        "global_load_dwordx4 %0, %8, off sc0 sc1\n\t"
        "global_load_dwordx4 %1, %8, off offset:64 sc0 sc1\n\t"
        "global_load_dwordx4 %2, %8, off offset:128 sc0 sc1\n\t"
        "global_load_dwordx4 %3, %8, off offset:192 sc0 sc1\n\t"
        "global_load_dwordx4 %4, %8, off offset:256 sc0 sc1\n\t"
        "global_load_dwordx4 %5, %8, off offset:320 sc0 sc1\n\t"
        "global_load_dwordx4 %6, %8, off offset:384 sc0 sc1\n\t"
        "global_load_dwordx4 %7, %8, off offset:448 sc0 sc1\n\t"
        "s_waitcnt vmcnt(0)"
        : "=&v"(a0), "=&v"(a1), "=&v"(a2), "=&v"(a3),
          "=&v"(a4), "=&v"(a5), "=&v"(a6), "=&v"(a7)
        : "v"(p) : "memory");
    d[0] = __builtin_bit_cast(bf16x8, a0); d[1] = __builtin_bit_cast(bf16x8, a1);
    d[2] = __builtin_bit_cast(bf16x8, a2); d[3] = __builtin_bit_cast(bf16x8, a3);
    d[4] = __builtin_bit_cast(bf16x8, a4); d[5] = __builtin_bit_cast(bf16x8, a5);
    d[6] = __builtin_bit_cast(bf16x8, a6); d[7] = __builtin_bit_cast(bf16x8, a7);
}

// Per-wave tag poll: lane li<16 polls producer-layer tag li, lanes 16..31 poll
// partner-layer tags (back-pressure), rest trivially true; wave exits via __all.
// ONE latency leg (one dword per lane, each tag in its own 64B slot).
__device__ __forceinline__ void tag_poll(const int* tagp, int tgt) {
    for (;;) {
        int tv = cload_int(tagp);
        if (__all(tv >= tgt)) break;
    }
}

// ---------------- layer 0: q = gate-chunk 0..3 ----------------
__device__ void run_l0(const float* __restrict__ x, const float* __restrict__ Wih0,
                       const float* __restrict__ Whh0, const float* __restrict__ bih0,
                       const float* __restrict__ bhh0, short* __restrict__ h1ring,
                       int* __restrict__ tags0, int* __restrict__ tags1, int g, int q)
{
    const int lane = threadIdx.x & 63, wv = threadIdx.x >> 6;
    const int n = lane & 15, quad = lane >> 4;
    const int hu_base = q * 64 + wv * 16;
    bf16x8 wf[4][9];
    float  bias[4];
    #pragma unroll
    for (int G = 0; G < 4; ++G) {
        int col = G * 256 + hu_base + n;              // gate row of W (4H x K)
        bias[G] = bih0[col] + bhh0[col];
        #pragma unroll
        for (int kt = 0; kt < 8; ++kt) {
            const float* p = Whh0 + (long)col * H_ + kt * 32 + quad * 8;
            bf16x8 v;
            #pragma unroll
            for (int j = 0; j < 8; ++j) v[j] = f2bf(p[j]);
            wf[G][kt] = v;
        }
        bf16x8 v = zero8();                           // x tile: K=16, pad to 32
        if (quad < 2) {
            const float* p = Wih0 + (long)col * NM_ + quad * 8;
            #pragma unroll
            for (int j = 0; j < 8; ++j) v[j] = f2bf(p[j]);
        }
        wf[G][8] = v;
    }
    const int bRow = g * 16 + n;
    // poll targets: lanes 0-15 -> peers' tags0 >= t (h1(t-1) published);
    // lanes 16-31 -> tags1 >= t-15 (ring slot t&15 consumed); others always-true.
    const int* tagp = (lane < 16) ? (tags0 + (g * 16 + lane) * 16)
                    : (lane < 32) ? (tags1 + (g * 16 + lane - 16) * 16)
                                  : (tags0 + g * 16 * 16);
    int* mytag = tags0 + (g * 16 + q * 4 + wv) * 16;
    f32x4 c = {0.f, 0.f, 0.f, 0.f};
    for (int t = 0; t < S_; ++t) {
        bf16x8 xfrag = zero8();                       // partner-independent, overlaps poll
        if (quad < 2) {
            const float* p = x + ((long)bRow * S_ + t) * NM_ + quad * 8;
            #pragma unroll
            for (int j = 0; j < 8; ++j) xfrag[j] = f2bf(p[j]);
        }
        const int tgt = (lane < 16) ? t : ((lane < 32) ? (t - 15) : NEG_INF_TGT);
        tag_poll(tagp, tgt);                          // leg 1

        bf16x8 af[9];
        if (t > 0) {                                  // leg 2
            cload8x16(h1ring + ((long)((t - 1) & 15) * B_ + bRow) * H_ + quad * 8, af);
        } else {
            #pragma unroll
            for (int kt = 0; kt < 8; ++kt) af[kt] = zero8();
        }
        af[8] = xfrag;

        f32x4 acc[4];
        #pragma unroll
        for (int G = 0; G < 4; ++G) {
            acc[G][0] = bias[G]; acc[G][1] = bias[G];
            acc[G][2] = bias[G]; acc[G][3] = bias[G];
        }
        #pragma unroll
        for (int kt = 0; kt < 9; ++kt)
            #pragma unroll
            for (int G = 0; G < 4; ++G)
                acc[G] = __builtin_amdgcn_mfma_f32_16x16x32_bf16(af[kt], wf[G][kt], acc[G], 0, 0, 0);
        #pragma unroll
        for (int r = 0; r < 4; ++r) {
            float iv = sigf(acc[0][r]);
            float fv = sigf(acc[1][r]);
            float gv = tanh_(acc[2][r]);
            float ov = sigf(acc[3][r]);
            c[r] = fv * c[r] + iv * gv;
            float hv = ov * tanh_(c[r]);
            int b = g * 16 + quad * 4 + r;            // C/D: row = quad*4+reg
            cstore_short(h1ring + ((long)(t & 15) * B_ + b) * H_ + hu_base + n,
                         (int)(unsigned short)f2bf(hv));
        }
        vm_drain();                                    // this wave's stores at L3
        if (lane == 0) cstore_int(mytag, t + 1);       // per-wave publish, no barrier
    }
}

// ---------------- layer 1 (K = 512: Whh1 | Wih1 fused) ----------------
__device__ void run_l1(const float* __restrict__ Wih1, const float* __restrict__ Whh1,
                       const float* __restrict__ bih1, const float* __restrict__ bhh1,
                       short* __restrict__ h1ring, short* __restrict__ h2ring,
                       float* __restrict__ hlast,
                       int* __restrict__ tags0, int* __restrict__ tags1, int g, int q)
{
    const int lane = threadIdx.x & 63, wv = threadIdx.x >> 6;
    const int n = lane & 15, quad = lane >> 4;
    const int hu_base = q * 64 + wv * 16;
    bf16x8 wf[4][16];
    float  bias[4];
    #pragma unroll
    for (int G = 0; G < 4; ++G) {
        int col = G * 256 + hu_base + n;
        bias[G] = bih1[col] + bhh1[col];
        #pragma unroll
        for (int kt = 0; kt < 8; ++kt) {
            const float* p = Whh1 + (long)col * H_ + kt * 32 + quad * 8;
            bf16x8 v;
            #pragma unroll
            for (int j = 0; j < 8; ++j) v[j] = f2bf(p[j]);
            wf[G][kt] = v;
        }
        #pragma unroll
        for (int kt = 0; kt < 8; ++kt) {
            const float* p = Wih1 + (long)col * H_ + kt * 32 + quad * 8;
            bf16x8 v;
            #pragma unroll
            for (int j = 0; j < 8; ++j) v[j] = f2bf(p[j]);
            wf[G][8 + kt] = v;
        }
    }
    const int bRow = g * 16 + n;
    // lanes 0-15 -> tags0 >= t+1 (h1(t) ready); 16-31 -> peers' tags1 >= t (h2(t-1) ready)
    const int* tagp = (lane < 16) ? (tags0 + (g * 16 + lane) * 16)
                    : (lane < 32) ? (tags1 + (g * 16 + lane - 16) * 16)
                                  : (tags1 + g * 16 * 16);
    int* mytag = tags1 + (g * 16 + q * 4 + wv) * 16;
    f32x4 c = {0.f, 0.f, 0.f, 0.f};
    for (int t = 0; t < S_; ++t) {
        const int tgt = (lane < 16) ? (t + 1) : ((lane < 32) ? t : NEG_INF_TGT);
        tag_poll(tagp, tgt);                          // leg 1

        bf16x8 af[16];
        if (t > 0) {                                  // leg 2
            cload8x16(h2ring + ((long)((t - 1) & 1) * B_ + bRow) * H_ + quad * 8, af);
        } else {
            #pragma unroll
            for (int kt = 0; kt < 8; ++kt) af[kt] = zero8();
        }
        cload8x16(h1ring + ((long)(t & 15) * B_ + bRow) * H_ + quad * 8, af + 8);  // leg 3

        f32x4 acc[4];
        #pragma unroll
        for (int G = 0; G < 4; ++G) {
            acc[G][0] = bias[G]; acc[G][1] = bias[G];
            acc[G][2] = bias[G]; acc[G][3] = bias[G];
        }
        #pragma unroll
        for (int kt = 0; kt < 16; ++kt)
            #pragma unroll
            for (int G = 0; G < 4; ++G)
                acc[G] = __builtin_amdgcn_mfma_f32_16x16x32_bf16(af[kt], wf[G][kt], acc[G], 0, 0, 0);
        #pragma unroll
        for (int r = 0; r < 4; ++r) {
            float iv = sigf(acc[0][r]);
            float fv = sigf(acc[1][r]);
            float gv = tanh_(acc[2][r]);
            float ov = sigf(acc[3][r]);
            c[r] = fv * c[r] + iv * gv;
            float hv = ov * tanh_(c[r]);
            int b = g * 16 + quad * 4 + r;
            cstore_short(h2ring + ((long)(t & 1) * B_ + b) * H_ + hu_base + n,
                         (int)(unsigned short)f2bf(hv));
            if (t == S_ - 1) hlast[b * H_ + hu_base + n] = hv;   // read next dispatch
        }
        vm_drain();
        if (lane == 0) cstore_int(mytag, t + 1);
    }
}

// 64 blocks: g = bx&7 (batch group), role = bx>>3 (0-3: L0 chunk, 4-7: L1 chunk).
// No __syncthreads anywhere: waves are decoupled via per-wave padded tags.
__global__ __launch_bounds__(256, 1) void lstm_kernel(
    const float* __restrict__ x,
    const float* __restrict__ Wih0, const float* __restrict__ Whh0,
    const float* __restrict__ bih0, const float* __restrict__ bhh0,
    const float* __restrict__ Wih1, const float* __restrict__ Whh1,
    const float* __restrict__ bih1, const float* __restrict__ bhh1,
    short* __restrict__ h1ring, short* __restrict__ h2ring,
    float* __restrict__ hlast,
    int* __restrict__ tags0, int* __restrict__ tags1)
{
    const int g    = blockIdx.x & 7;
    const int role = blockIdx.x >> 3;
    if (role < 4) run_l0(x, Wih0, Whh0, bih0, bhh0, h1ring, tags0, tags1, g, role);
    else          run_l1(Wih1, Whh1, bih1, bhh1, h1ring, h2ring, hlast, tags0, tags1, g, role - 4);
}

__device__ __forceinline__ float blockSum(float v, float* sbuf) {
    #pragma unroll
    for (int off = 32; off > 0; off >>= 1) v += __shfl_down(v, off, 64);
    __syncthreads();
    if ((threadIdx.x & 63) == 0) sbuf[threadIdx.x >> 6] = v;
    __syncthreads();
    return sbuf[0] + sbuf[1] + sbuf[2] + sbuf[3];
}

// LayerNorm + logits softmax + budgets softmax + beta + VIX override. One block per batch row.
__global__ __launch_bounds__(256) void tail_kernel(
    const float* __restrict__ hlast, const float* __restrict__ gamma,
    const float* __restrict__ lnbeta, const float* __restrict__ Wl,
    const float* __restrict__ bl, const float* __restrict__ rb,
    const float* __restrict__ vix, float* __restrict__ out)
{
    __shared__ float sbuf[4];
    __shared__ float pr[3], mxs[3], dens[3];
    __shared__ float bvec[32];
    const int b   = blockIdx.x;
    const int tid = threadIdx.x;

    float v  = hlast[b * H_ + tid];
    float mu = blockSum(v, sbuf) * (1.0f / 256.0f);
    float d  = v - mu;
    float var = blockSum(d * d, sbuf) * (1.0f / 256.0f);
    float hn  = d * rsqrtf(var + 1e-5f) * gamma[tid] + lnbeta[tid];

    float l[3];
    #pragma unroll
    for (int k = 0; k < 3; ++k)
        l[k] = blockSum(hn * Wl[k * H_ + tid], sbuf) + bl[k];

    if (tid == 0) {
        float m  = fmaxf(l[0], fmaxf(l[1], l[2]));
        float e0 = __expf(l[0] - m), e1 = __expf(l[1] - m), e2 = __expf(l[2] - m);
        float dn = e0 + e1 + e2;
        pr[0] = e0 / dn; pr[1] = e1 / dn; pr[2] = e2 / dn;
    }
    if (tid < 3) {
        float m = -1e30f;
        for (int p = 0; p < 32; ++p) m = fmaxf(m, rb[tid * 32 + p]);
        float dn = 0.f;
        for (int p = 0; p < 32; ++p) dn += __expf(rb[tid * 32 + p] - m);
        mxs[tid] = m; dens[tid] = dn;
    }
    __syncthreads();
    if (tid < 32) {
        float bp = 0.f;
        #pragma unroll
        for (int k = 0; k < 3; ++k)
            bp += pr[k] * __expf(rb[k * 32 + tid] - mxs[k]) / dens[k];
        bvec[tid] = bp;
    }
    __syncthreads();
    if (tid == 0) {
        bool  mask = vix[b] >= 30.0f;
        float eq_total = 0.f, cur_def = 0.f;
        for (int p = 0; p < 24; ++p) eq_total += bvec[p];
        for (int p = 24; p < 32; ++p) cur_def += bvec[p];
        float shortfall = 0.4f - cur_def;
        float ratio = fminf(shortfall / fmaxf(eq_total, 1e-8f), 0.8f);
        bool  apply = mask && (shortfall > 0.0f) && (eq_total > 1e-8f);
        float bb[32]; float ssum = 0.f;
        for (int p = 0; p < 32; ++p) {
            float b2 = (p < 24) ? bvec[p] * (1.0f - ratio) : bvec[p] + shortfall * (1.0f / 8.0f);
            float bv = apply ? b2 : bvec[p];
            bb[p] = bv; ssum += bv;
        }
        float inv = 1.0f / (ssum + 1e-8f);
        for (int p = 0; p < 32; ++p)
            out[b * 32 + p] = mask ? bb[p] * inv : bvec[p];
        #pragma unroll
        for (int k = 0; k < 3; ++k)
            out[B_ * 32 + b * 3 + k] = pr[k];
    }
}

extern "C" void kernel_launch(void* const* d_in, const int* in_sizes, int n_in,
                              void* d_out, int out_size, void* d_ws, size_t ws_size,
                              hipStream_t stream)
{
    const float* x    = (const float*)d_in[0];
    const float* vix  = (const float*)d_in[1];
    const float* Wih0 = (const float*)d_in[2];
    const float* Whh0 = (const float*)d_in[3];
    const float* bih0 = (const float*)d_in[4];
    const float* bhh0 = (const float*)d_in[5];
    const float* Wih1 = (const float*)d_in[6];
    const float* Whh1 = (const float*)d_in[7];
    const float* bih1 = (const float*)d_in[8];
    const float* bhh1 = (const float*)d_in[9];
    const float* lng  = (const float*)d_in[10];
    const float* lnb  = (const float*)d_in[11];
    const float* Wl   = (const float*)d_in[12];
    const float* bl   = (const float*)d_in[13];
    const float* rb   = (const float*)d_in[14];
    float* out = (float*)d_out;

    // ws layout (~1.33 MB):
    //   h1ring bf16 [16][128][256] : 1048576 B @ 0         (tag-protected, no init)
    //   h2ring bf16 [2][128][256]  : 131072 B  @ 1048576   (tag-protected, no init)
    //   hlast  f32  [128][256]     : 131072 B  @ 1179648
    //   tags0: 128 waves x 64B     : 8192 B    @ 1310720   (memset 0)
    //   tags1: 128 waves x 64B     : 8192 B    @ 1318912   (memset 0)
    char*  ws     = (char*)d_ws;
    short* h1ring = (short*)ws;
    short* h2ring = (short*)(ws + 1048576);
    float* hlast  = (float*)(ws + 1179648);
    int*   tags0  = (int*)(ws + 1310720);
    int*   tags1  = (int*)(ws + 1318912);

    hipMemsetAsync(ws + 1310720, 0, 16384, stream);   // zero both tag arrays
    lstm_kernel<<<64, 256, 0, stream>>>(x, Wih0, Whh0, bih0, bhh0,
                                        Wih1, Whh1, bih1, bhh1,
                                        h1ring, h2ring, hlast, tags0, tags1);
    tail_kernel<<<128, 256, 0, stream>>>(hlast, lng, lnb, Wl, bl, rb, vix, out);
}